// Round 15
// baseline (196.660 us; speedup 1.0000x reference)
//
#include <hip/hip_runtime.h>

// Problem constants
#define TT 2048
#define DD 1024
#define NH 16
#define DH 64
#define MR 4096            // B*T rows

typedef __attribute__((ext_vector_type(8))) short bf16x8;
typedef __attribute__((ext_vector_type(4))) short bf16x4;
typedef __attribute__((ext_vector_type(4))) float f32x4;
typedef __attribute__((ext_vector_type(2))) unsigned int u32x2;

__device__ __forceinline__ float bf2f(unsigned short u) {
  unsigned int x = ((unsigned int)u) << 16;
  return __builtin_bit_cast(float, x);
}
__device__ __forceinline__ unsigned short f2bf(float f) {
  unsigned int x = __builtin_bit_cast(unsigned int, f);
  x = (x + 0x7fffu + ((x >> 16) & 1u)) >> 16;
  return (unsigned short)x;
}
__device__ __forceinline__ unsigned int pack_bf2(float a, float b) {
#if __has_builtin(__builtin_amdgcn_cvt_pk_bf16_f32)
  typedef __attribute__((ext_vector_type(2))) __bf16 bf2_t;
  bf2_t v = __builtin_amdgcn_cvt_pk_bf16_f32(a, b);
  return __builtin_bit_cast(unsigned int, v);
#else
  return (unsigned int)f2bf(a) | ((unsigned int)f2bf(b) << 16);
#endif
}
__device__ __forceinline__ bf16x8 load8(const float* p) {
  bf16x8 r;
#pragma unroll
  for (int e = 0; e < 8; ++e) r[e] = (short)f2bf(p[e]);
  return r;
}

#if __has_builtin(__builtin_amdgcn_mfma_f32_16x16x16_bf16)
#define MFMA_K16(A, B, C) __builtin_amdgcn_mfma_f32_16x16x16_bf16(A, B, C, 0, 0, 0)
#else
#define MFMA_K16(A, B, C) __builtin_amdgcn_mfma_f32_16x16x16bf16_1k(A, B, C, 0, 0, 0)
#endif

// Async global->LDS 16B/lane; LDS base wave-uniform, HW adds lane*16.
__device__ __forceinline__ void stage16(const unsigned short* g,
                                        unsigned short* lbase, int lane) {
#if __has_builtin(__builtin_amdgcn_global_load_lds)
  __builtin_amdgcn_global_load_lds(
      (const __attribute__((address_space(1))) unsigned int*)g,
      (__attribute__((address_space(3))) unsigned int*)(lbase + lane * 8),
      16, 0, 0);
#else
  *(bf16x8*)(lbase + lane * 8) = *(const bf16x8*)g;
#endif
}

// ---------------------------------------------------------------------------
// Convert: Wb rows = [Wk; Wq; Wv; Wo] (reference Q/K swap!) + x -> xb.
// xb lives in d_out (dead until gemm_out) so the async-A path is guaranteed.
// ---------------------------------------------------------------------------
__global__ __launch_bounds__(256) void cvt_all(
    const float* __restrict__ Wq, const float* __restrict__ Wk,
    const float* __restrict__ Wv, const float* __restrict__ Wo,
    const float* __restrict__ x,
    unsigned short* __restrict__ Wb, unsigned short* __restrict__ xb)
{
  int c = blockIdx.x * 256 + threadIdx.x;     // chunk of 8 elems
  if (c < 524288) {
    int idx = c * 8, n = idx >> 10, col = idx & 1023;
    const float* src = (n < 1024) ? Wk + (size_t)n * 1024
                     : (n < 2048) ? Wq + (size_t)(n - 1024) * 1024
                     : (n < 3072) ? Wv + (size_t)(n - 2048) * 1024
                                  : Wo + (size_t)(n - 3072) * 1024;
    *(bf16x8*)&Wb[idx] = load8(src + col);
  } else {
    size_t idx = (size_t)(c - 524288) * 8;
    *(bf16x8*)&xb[idx] = load8(&x[idx]);
  }
}

// ---------------------------------------------------------------------------
// Fused QKV projection, XCD-affine decode, both operands async-staged.
// ---------------------------------------------------------------------------
__global__ __launch_bounds__(256) void gemm_qkv(
    const unsigned short* __restrict__ xb,
    const unsigned short* __restrict__ Wb,
    unsigned short* __restrict__ Q, unsigned short* __restrict__ Kb,
    unsigned short* __restrict__ Vt)
{
  __shared__ unsigned short pool[8704];      // As(4096)+Bs(4096) | Tt(8704)
  unsigned short* As = pool;
  unsigned short* Bs = pool + 4096;

  const int tid = threadIdx.x, wave = tid >> 6, lane = tid & 63;
  const int lr = lane & 15, quad = lane >> 4;
  const int cblk = blockIdx.x;               // 0..767
  const int xcd = cblk & 7, kk = cblk >> 3;  // kk 0..95
  const int bm = (xcd + (kk / 24) * 8) * 128;
  const int bn = (kk % 24) * 128;
  const int wm = (wave >> 1) * 64, wn = (wave & 1) * 64;

  f32x4 acc[4][4] = {};

  for (int k0 = 0; k0 < 1024; k0 += 32) {
#pragma unroll
    for (int i = 0; i < 2; ++i) {
      int c = wave * 128 + i * 64 + lane;    // chunk 0..511
      int row = c >> 2, l8 = (c & 3) ^ ((row >> 1) & 3);
      stage16(&Wb[(size_t)(bn + row) * 1024 + k0 + l8 * 8],
              &Bs[(wave * 2 + i) * 512], lane);
      stage16(&xb[(size_t)(bm + row) * 1024 + k0 + l8 * 8],
              &As[(wave * 2 + i) * 512], lane);
    }
    __syncthreads();

    bf16x8 af[4], bf[4];
#pragma unroll
    for (int mt = 0; mt < 4; ++mt) {
      int row = wm + mt * 16 + lr;
      af[mt] = *(const bf16x8*)&As[row * 32 + (quad ^ ((row >> 1) & 3)) * 8];
    }
#pragma unroll
    for (int nt = 0; nt < 4; ++nt) {
      int row = wn + nt * 16 + lr;
      bf[nt] = *(const bf16x8*)&Bs[row * 32 + (quad ^ ((row >> 1) & 3)) * 8];
    }
#pragma unroll
    for (int mt = 0; mt < 4; ++mt)
#pragma unroll
      for (int nt = 0; nt < 4; ++nt)
        acc[mt][nt] = __builtin_amdgcn_mfma_f32_16x16x32_bf16(
            af[mt], bf[nt], acc[mt][nt], 0, 0, 0);
    __syncthreads();
  }

  if (bn < 2048) {
    unsigned short* Cp = (bn < 1024) ? Q : Kb;
    int coff = (bn < 1024) ? bn : bn - 1024;
#pragma unroll
    for (int nt = 0; nt < 4; ++nt) {
      int col = coff + wn + nt * 16 + lr;
#pragma unroll
      for (int mt = 0; mt < 4; ++mt) {
        int row = bm + wm + mt * 16 + quad * 4;
#pragma unroll
        for (int r = 0; r < 4; ++r)
          Cp[(size_t)(row + r) * 1024 + col] = f2bf(acc[mt][nt][r]);
      }
    }
  } else {
    const int b = bm >> 11, t0 = bm & 2047, d0 = bn - 2048;
    unsigned short* Tt = pool;               // [64][136]
#pragma unroll
    for (int hv = 0; hv < 2; ++hv) {
      __syncthreads();
      if ((wave & 1) == hv) {
#pragma unroll
        for (int nt = 0; nt < 4; ++nt)
#pragma unroll
          for (int mt = 0; mt < 4; ++mt)
#pragma unroll
            for (int r = 0; r < 4; ++r)
              Tt[(nt * 16 + lr) * 136 + wm + mt * 16 + quad * 4 + r] =
                  f2bf(acc[mt][nt][r]);
      }
      __syncthreads();
#pragma unroll
      for (int ch = 0; ch < 4; ++ch) {
        int cc = tid + ch * 256;
        int d64 = cc >> 4, t8 = cc & 15;
        int dg = d0 + hv * 64 + d64;
        int h = dg >> 6, d = dg & 63;
        bf16x8 v = *(const bf16x8*)&Tt[d64 * 136 + t8 * 8];
        *(bf16x8*)&Vt[(((size_t)(b * NH + h) * 64 + d) << 11) + t0 + t8 * 8] = v;
      }
    }
  }
}

// ---------------------------------------------------------------------------
// Flash attention (R14 verbatim: single-buffered, XCD-affine bh decode,
// Sᵀ formulation, packed-bf16 P, MFMA-ones l, p<->31-p pairing).
// ---------------------------------------------------------------------------
__global__ __launch_bounds__(256) void attn(
    const unsigned short* __restrict__ Q,
    const unsigned short* __restrict__ Kb,
    const unsigned short* __restrict__ Vt,
    unsigned short* __restrict__ ctx)
{
  __shared__ unsigned short Ks[128 * 64];    // [kseq][d]   8 chunks/row
  __shared__ unsigned short Vs[64 * 128];    // [d][t]     16 chunks/row

  const int tid = threadIdx.x, wave = tid >> 6, lane = tid & 63;
  const int lr = lane & 15, quad = lane >> 4;
  const int p  = blockIdx.x >> 5;                               // 0..15
  const int bh = (blockIdx.x & 7) | (((blockIdx.x >> 3) & 3) << 3);
  const int h = bh & 15, b = bh >> 4;

  const size_t qkbase = ((size_t)b * TT) * 1024 + h * 64;
  const size_t vbase  = ((size_t)(b * NH + h) * 64) << 11;
  const float QS = 0.125f * 1.44269504f;     // scale * log2(e)

  bf16x4 ones;
#pragma unroll
  for (int e = 0; e < 4; ++e) ones[e] = (short)0x3F80;   // bf16 1.0

#pragma unroll
  for (int pass = 0; pass < 2; ++pass) {
    const int qt = pass ? p : (31 - p);
    const int qrow0 = qt * 64 + wave * 16;
    const int qrow  = qrow0 + lr;

    bf16x8 qf[2];
#pragma unroll
    for (int kb = 0; kb < 2; ++kb) {
      bf16x8 raw = *(const bf16x8*)&Q[qkbase + (size_t)(qrow0 + lr) * 1024 + kb * 32 + quad * 8];
#pragma unroll
      for (int e = 0; e < 8; ++e)
        qf[kb][e] = (short)f2bf(bf2f((unsigned short)raw[e]) * QS);
    }

    float m_i = -1e30f;
    f32x4 od[4] = {};
    f32x4 ol = {};
    const int jmax = qt >> 1;

    for (int j = 0; j <= jmax; ++j) {
#pragma unroll
      for (int i = 0; i < 4; ++i) {
        int ci = (wave * 4 + i) * 64 + lane;
        int row = ci >> 3, lc = (ci & 7) ^ (row & 7);
        stage16(&Kb[qkbase + (size_t)(j * 128 + row) * 1024 + lc * 8],
                &Ks[(wave * 4 + i) * 512], lane);
      }
#pragma unroll
      for (int i = 0; i < 4; ++i) {
        int ci = (wave * 4 + i) * 64 + lane;
        int d = ci >> 4, lc = (ci & 15) ^ (d & 15);
        stage16(&Vt[vbase + ((size_t)d << 11) + j * 128 + lc * 8],
                &Vs[(wave * 4 + i) * 512], lane);
      }
      __syncthreads();

      const bool diag = (j == jmax);
      const int nlim = (diag && !(qt & 1)) ? 4 : 8;

      f32x4 s[8];
#pragma unroll
      for (int nt = 0; nt < 8; ++nt)
        if (nt < nlim) {
          f32x4 a = {0.f, 0.f, 0.f, 0.f};
#pragma unroll
          for (int kb = 0; kb < 2; ++kb) {
            int pc = (kb * 4 + quad) ^ (lr & 7);
            bf16x8 kf = *(const bf16x8*)&Ks[(nt * 16 + lr) * 64 + pc * 8];
            a = __builtin_amdgcn_mfma_f32_16x16x32_bf16(kf, qf[kb], a, 0, 0, 0);
          }
          s[nt] = a;
        }

      if (diag) {
#pragma unroll
        for (int nt = 0; nt < 8; ++nt)
          if (nt < nlim)
#pragma unroll
            for (int r = 0; r < 4; ++r) {
              int kpos = j * 128 + nt * 16 + quad * 4 + r;
              if (kpos > qrow) s[nt][r] = -1e30f;
            }
      }

      float mloc = -1e30f;
#pragma unroll
      for (int nt = 0; nt < 8; ++nt)
        if (nt < nlim)
#pragma unroll
          for (int r = 0; r < 4; ++r) mloc = fmaxf(mloc, s[nt][r]);
      mloc = fmaxf(mloc, __shfl_xor(mloc, 16, 64));
      mloc = fmaxf(mloc, __shfl_xor(mloc, 32, 64));
      float mnew = fmaxf(m_i, mloc);
      float alpha = exp2f(m_i - mnew);
      m_i = mnew;

      bf16x4 pk[8];
#pragma unroll
      for (int nt = 0; nt < 8; ++nt)
        if (nt < nlim) {
          float p0 = exp2f(s[nt][0] - mnew), p1 = exp2f(s[nt][1] - mnew);
          float p2 = exp2f(s[nt][2] - mnew), p3 = exp2f(s[nt][3] - mnew);
          u32x2 u = {pack_bf2(p0, p1), pack_bf2(p2, p3)};
          pk[nt] = __builtin_bit_cast(bf16x4, u);
        }

      float am[4];
#pragma unroll
      for (int r = 0; r < 4; ++r) am[r] = __shfl(alpha, quad * 4 + r, 16);
#pragma unroll
      for (int dt = 0; dt < 4; ++dt)
#pragma unroll
        for (int r = 0; r < 4; ++r) od[dt][r] *= am[r];
#pragma unroll
      for (int r = 0; r < 4; ++r) ol[r] *= am[r];

#pragma unroll
      for (int nt = 0; nt < 8; ++nt)
        if (nt < nlim) {
#pragma unroll
          for (int dt = 0; dt < 4; ++dt) {
            int pc = (nt * 2 + (quad >> 1)) ^ lr;
            bf16x4 vf = *(const bf16x4*)&Vs[(dt * 16 + lr) * 128 + pc * 8 + (quad & 1) * 4];
            od[dt] = MFMA_K16(pk[nt], vf, od[dt]);
          }
          ol = MFMA_K16(pk[nt], ones, ol);
        }
      __syncthreads();
    }

#pragma unroll
    for (int dt = 0; dt < 4; ++dt) {
      int col = h * 64 + dt * 16 + lr;
#pragma unroll
      for (int r = 0; r < 4; ++r) {
        int row = qrow0 + quad * 4 + r;
        ctx[((size_t)b * TT + row) * 1024 + col] = f2bf(od[dt][r] / ol[r]);
      }
    }
  }
}

// ---------------------------------------------------------------------------
// Output projection with XCD-affine decode (unchanged from R12/R14).
// ---------------------------------------------------------------------------
__global__ __launch_bounds__(256) void gemm_out(
    const unsigned short* __restrict__ A,
    const unsigned short* __restrict__ Bw,
    const float* __restrict__ bias,
    float* __restrict__ out)
{
  __shared__ unsigned short pool[8192];
  unsigned short* As = pool;
  unsigned short* Bs = pool + 4096;

  const int tid = threadIdx.x, wave = tid >> 6, lane = tid & 63;
  const int lr = lane & 15, quad = lane >> 4;
  const int cblk = blockIdx.x;               // 0..255
  const int xcd = cblk & 7, kk = cblk >> 3;  // kk 0..31
  const int bm = (xcd + (kk / 8) * 8) * 128;
  const int bn = (kk % 8) * 128;
  const int wm = (wave >> 1) * 64, wn = (wave & 1) * 64;

  f32x4 acc[4][4] = {};

  for (int k0 = 0; k0 < 1024; k0 += 32) {
#pragma unroll
    for (int i = 0; i < 2; ++i) {
      int c = wave * 128 + i * 64 + lane;
      int row = c >> 2, l8 = (c & 3) ^ ((row >> 1) & 3);
      stage16(&A[(size_t)(bm + row) * 1024 + k0 + l8 * 8],
              &As[(wave * 2 + i) * 512], lane);
      stage16(&Bw[(size_t)(bn + row) * 1024 + k0 + l8 * 8],
              &Bs[(wave * 2 + i) * 512], lane);
    }
    __syncthreads();

    bf16x8 af[4], bf[4];
#pragma unroll
    for (int mt = 0; mt < 4; ++mt) {
      int row = wm + mt * 16 + lr;
      af[mt] = *(const bf16x8*)&As[row * 32 + (quad ^ ((row >> 1) & 3)) * 8];
    }
#pragma unroll
    for (int nt = 0; nt < 4; ++nt) {
      int row = wn + nt * 16 + lr;
      bf[nt] = *(const bf16x8*)&Bs[row * 32 + (quad ^ ((row >> 1) & 3)) * 8];
    }
#pragma unroll
    for (int mt = 0; mt < 4; ++mt)
#pragma unroll
      for (int nt = 0; nt < 4; ++nt)
        acc[mt][nt] = __builtin_amdgcn_mfma_f32_16x16x32_bf16(
            af[mt], bf[nt], acc[mt][nt], 0, 0, 0);
    __syncthreads();
  }

#pragma unroll
  for (int nt = 0; nt < 4; ++nt) {
    int col = bn + wn + nt * 16 + lr;
    float bv = bias[col];
#pragma unroll
    for (int mt = 0; mt < 4; ++mt) {
      int row = bm + wm + mt * 16 + quad * 4;
#pragma unroll
      for (int r = 0; r < 4; ++r)
        out[(size_t)(row + r) * 1024 + col] = acc[mt][nt][r] + bv;
    }
  }
}

// ---------------------------------------------------------------------------
extern "C" void kernel_launch(void* const* d_in, const int* in_sizes, int n_in,
                              void* d_out, int out_size, void* d_ws, size_t ws_size,
                              hipStream_t stream) {
  const float* x  = (const float*)d_in[0];
  const float* Wq = (const float*)d_in[1];
  const float* Wk = (const float*)d_in[2];
  const float* Wv = (const float*)d_in[3];
  const float* Wv_ = Wv; (void)Wv_;
  const float* Wo = (const float*)d_in[4];
  const float* bo = (const float*)d_in[5];
  float* out = (float*)d_out;
  unsigned short* ws = (unsigned short*)d_ws;

  const size_t SZ = (size_t)MR * DD;         // 4096*1024

  // ws: [0] Q (ctx in-place)  [1] K  [2] Vt[b][h][d][t]  [3] Wb
  // xb (bf16 x, 8 MB) lives in d_out (16 MB fp32): dead until gemm_out's
  // final write, so the async-A staging path is ALWAYS available.
  unsigned short* Qb  = ws;
  unsigned short* Kbf = ws + SZ;
  unsigned short* Vt  = ws + 2 * SZ;
  unsigned short* Wb  = ws + 3 * SZ;
  unsigned short* xb  = (unsigned short*)d_out;

  cvt_all<<<dim3(4096), 256, 0, stream>>>(Wq, Wk, Wv, Wo, x, Wb, xb);
  gemm_qkv<<<dim3(768), 256, 0, stream>>>(xb, Wb, Qb, Kbf, Vt);
  attn<<<dim3(2 * NH * 16), 256, 0, stream>>>(Qb, Kbf, Vt, Qb);
  gemm_out<<<dim3(256), 256, 0, stream>>>(Qb, Wb + 3 * (size_t)DD * DD, bo, out);
}

// Round 16
// 193.293 us; speedup vs baseline: 1.0174x; 1.0174x over previous
//
#include <hip/hip_runtime.h>

// Problem constants
#define TT 2048
#define DD 1024
#define NH 16
#define DH 64
#define MR 4096            // B*T rows

typedef __attribute__((ext_vector_type(8))) short bf16x8;
typedef __attribute__((ext_vector_type(4))) short bf16x4;
typedef __attribute__((ext_vector_type(4))) float f32x4;
typedef __attribute__((ext_vector_type(2))) unsigned int u32x2;

__device__ __forceinline__ float bf2f(unsigned short u) {
  unsigned int x = ((unsigned int)u) << 16;
  return __builtin_bit_cast(float, x);
}
__device__ __forceinline__ unsigned short f2bf(float f) {
  unsigned int x = __builtin_bit_cast(unsigned int, f);
  x = (x + 0x7fffu + ((x >> 16) & 1u)) >> 16;
  return (unsigned short)x;
}
__device__ __forceinline__ unsigned int pack_bf2(float a, float b) {
#if __has_builtin(__builtin_amdgcn_cvt_pk_bf16_f32)
  typedef __attribute__((ext_vector_type(2))) __bf16 bf2_t;
  bf2_t v = __builtin_amdgcn_cvt_pk_bf16_f32(a, b);
  return __builtin_bit_cast(unsigned int, v);
#else
  return (unsigned int)f2bf(a) | ((unsigned int)f2bf(b) << 16);
#endif
}
__device__ __forceinline__ bf16x8 load8(const float* p) {
  bf16x8 r;
#pragma unroll
  for (int e = 0; e < 8; ++e) r[e] = (short)f2bf(p[e]);
  return r;
}

#if __has_builtin(__builtin_amdgcn_mfma_f32_16x16x16_bf16)
#define MFMA_K16(A, B, C) __builtin_amdgcn_mfma_f32_16x16x16_bf16(A, B, C, 0, 0, 0)
#else
#define MFMA_K16(A, B, C) __builtin_amdgcn_mfma_f32_16x16x16bf16_1k(A, B, C, 0, 0, 0)
#endif

// Async global->LDS 16B/lane; LDS base wave-uniform, HW adds lane*16.
__device__ __forceinline__ void stage16(const unsigned short* g,
                                        unsigned short* lbase, int lane) {
#if __has_builtin(__builtin_amdgcn_global_load_lds)
  __builtin_amdgcn_global_load_lds(
      (const __attribute__((address_space(1))) unsigned int*)g,
      (__attribute__((address_space(3))) unsigned int*)(lbase + lane * 8),
      16, 0, 0);
#else
  *(bf16x8*)(lbase + lane * 8) = *(const bf16x8*)g;
#endif
}

// ---------------------------------------------------------------------------
// Convert: Wb rows = [Wk; Wq; Wv; Wo] (reference Q/K swap!) + x -> xb.
// xb lives in d_out (dead until gemm_out) so the async-A path is guaranteed.
// ---------------------------------------------------------------------------
__global__ __launch_bounds__(256) void cvt_all(
    const float* __restrict__ Wq, const float* __restrict__ Wk,
    const float* __restrict__ Wv, const float* __restrict__ Wo,
    const float* __restrict__ x,
    unsigned short* __restrict__ Wb, unsigned short* __restrict__ xb)
{
  int c = blockIdx.x * 256 + threadIdx.x;     // chunk of 8 elems
  if (c < 524288) {
    int idx = c * 8, n = idx >> 10, col = idx & 1023;
    const float* src = (n < 1024) ? Wk + (size_t)n * 1024
                     : (n < 2048) ? Wq + (size_t)(n - 1024) * 1024
                     : (n < 3072) ? Wv + (size_t)(n - 2048) * 1024
                                  : Wo + (size_t)(n - 3072) * 1024;
    *(bf16x8*)&Wb[idx] = load8(src + col);
  } else {
    size_t idx = (size_t)(c - 524288) * 8;
    *(bf16x8*)&xb[idx] = load8(&x[idx]);
  }
}

// ---------------------------------------------------------------------------
// Fused QKV projection, XCD-affine decode, both operands async-staged
// (unchanged from R15).
// ---------------------------------------------------------------------------
__global__ __launch_bounds__(256) void gemm_qkv(
    const unsigned short* __restrict__ xb,
    const unsigned short* __restrict__ Wb,
    unsigned short* __restrict__ Q, unsigned short* __restrict__ Kb,
    unsigned short* __restrict__ Vt)
{
  __shared__ unsigned short pool[8704];      // As(4096)+Bs(4096) | Tt(8704)
  unsigned short* As = pool;
  unsigned short* Bs = pool + 4096;

  const int tid = threadIdx.x, wave = tid >> 6, lane = tid & 63;
  const int lr = lane & 15, quad = lane >> 4;
  const int cblk = blockIdx.x;               // 0..767
  const int xcd = cblk & 7, kk = cblk >> 3;  // kk 0..95
  const int bm = (xcd + (kk / 24) * 8) * 128;
  const int bn = (kk % 24) * 128;
  const int wm = (wave >> 1) * 64, wn = (wave & 1) * 64;

  f32x4 acc[4][4] = {};

  for (int k0 = 0; k0 < 1024; k0 += 32) {
#pragma unroll
    for (int i = 0; i < 2; ++i) {
      int c = wave * 128 + i * 64 + lane;    // chunk 0..511
      int row = c >> 2, l8 = (c & 3) ^ ((row >> 1) & 3);
      stage16(&Wb[(size_t)(bn + row) * 1024 + k0 + l8 * 8],
              &Bs[(wave * 2 + i) * 512], lane);
      stage16(&xb[(size_t)(bm + row) * 1024 + k0 + l8 * 8],
              &As[(wave * 2 + i) * 512], lane);
    }
    __syncthreads();

    bf16x8 af[4], bf[4];
#pragma unroll
    for (int mt = 0; mt < 4; ++mt) {
      int row = wm + mt * 16 + lr;
      af[mt] = *(const bf16x8*)&As[row * 32 + (quad ^ ((row >> 1) & 3)) * 8];
    }
#pragma unroll
    for (int nt = 0; nt < 4; ++nt) {
      int row = wn + nt * 16 + lr;
      bf[nt] = *(const bf16x8*)&Bs[row * 32 + (quad ^ ((row >> 1) & 3)) * 8];
    }
#pragma unroll
    for (int mt = 0; mt < 4; ++mt)
#pragma unroll
      for (int nt = 0; nt < 4; ++nt)
        acc[mt][nt] = __builtin_amdgcn_mfma_f32_16x16x32_bf16(
            af[mt], bf[nt], acc[mt][nt], 0, 0, 0);
    __syncthreads();
  }

  if (bn < 2048) {
    unsigned short* Cp = (bn < 1024) ? Q : Kb;
    int coff = (bn < 1024) ? bn : bn - 1024;
#pragma unroll
    for (int nt = 0; nt < 4; ++nt) {
      int col = coff + wn + nt * 16 + lr;
#pragma unroll
      for (int mt = 0; mt < 4; ++mt) {
        int row = bm + wm + mt * 16 + quad * 4;
#pragma unroll
        for (int r = 0; r < 4; ++r)
          Cp[(size_t)(row + r) * 1024 + col] = f2bf(acc[mt][nt][r]);
      }
    }
  } else {
    const int b = bm >> 11, t0 = bm & 2047, d0 = bn - 2048;
    unsigned short* Tt = pool;               // [64][136]
#pragma unroll
    for (int hv = 0; hv < 2; ++hv) {
      __syncthreads();
      if ((wave & 1) == hv) {
#pragma unroll
        for (int nt = 0; nt < 4; ++nt)
#pragma unroll
          for (int mt = 0; mt < 4; ++mt)
#pragma unroll
            for (int r = 0; r < 4; ++r)
              Tt[(nt * 16 + lr) * 136 + wm + mt * 16 + quad * 4 + r] =
                  f2bf(acc[mt][nt][r]);
      }
      __syncthreads();
#pragma unroll
      for (int ch = 0; ch < 4; ++ch) {
        int cc = tid + ch * 256;
        int d64 = cc >> 4, t8 = cc & 15;
        int dg = d0 + hv * 64 + d64;
        int h = dg >> 6, d = dg & 63;
        bf16x8 v = *(const bf16x8*)&Tt[d64 * 136 + t8 * 8];
        *(bf16x8*)&Vt[(((size_t)(b * NH + h) * 64 + d) << 11) + t0 + t8 * 8] = v;
      }
    }
  }
}

// ---------------------------------------------------------------------------
// Flash attention v8: R14 structure + SPLIT-BARRIER staging. K is staged and
// drained at barrier1 (~200cyc L2 exposed); V is staged AFTER barrier1 so its
// drain at barrier2 hides under QK+softmax compute; PV moves after barrier2.
// Ordering audit: Ks(j+1) writes follow b2(j) > others' QK(j) reads; Vs(j)
// writes follow b1(j) > others' PV(j-1) reads. XCD-affine bh decode keeps
// K/V L2-resident (FETCH 12MB); p<->31-p pairing keeps 17 iters/block.
// ---------------------------------------------------------------------------
__global__ __launch_bounds__(256) void attn(
    const unsigned short* __restrict__ Q,
    const unsigned short* __restrict__ Kb,
    const unsigned short* __restrict__ Vt,
    unsigned short* __restrict__ ctx)
{
  __shared__ unsigned short Ks[128 * 64];    // [kseq][d]   8 chunks/row
  __shared__ unsigned short Vs[64 * 128];    // [d][t]     16 chunks/row

  const int tid = threadIdx.x, wave = tid >> 6, lane = tid & 63;
  const int lr = lane & 15, quad = lane >> 4;
  const int p  = blockIdx.x >> 5;                               // 0..15
  const int bh = (blockIdx.x & 7) | (((blockIdx.x >> 3) & 3) << 3);
  const int h = bh & 15, b = bh >> 4;

  const size_t qkbase = ((size_t)b * TT) * 1024 + h * 64;
  const size_t vbase  = ((size_t)(b * NH + h) * 64) << 11;
  const float QS = 0.125f * 1.44269504f;     // scale * log2(e)

  bf16x4 ones;
#pragma unroll
  for (int e = 0; e < 4; ++e) ones[e] = (short)0x3F80;   // bf16 1.0

#pragma unroll
  for (int pass = 0; pass < 2; ++pass) {
    const int qt = pass ? p : (31 - p);
    const int qrow0 = qt * 64 + wave * 16;
    const int qrow  = qrow0 + lr;

    bf16x8 qf[2];
#pragma unroll
    for (int kb = 0; kb < 2; ++kb) {
      bf16x8 raw = *(const bf16x8*)&Q[qkbase + (size_t)(qrow0 + lr) * 1024 + kb * 32 + quad * 8];
#pragma unroll
      for (int e = 0; e < 8; ++e)
        qf[kb][e] = (short)f2bf(bf2f((unsigned short)raw[e]) * QS);
    }

    float m_i = -1e30f;
    f32x4 od[4] = {};
    f32x4 ol = {};
    const int jmax = qt >> 1;

    for (int j = 0; j <= jmax; ++j) {
      // ---- stage K, drain at barrier1 ----
#pragma unroll
      for (int i = 0; i < 4; ++i) {
        int ci = (wave * 4 + i) * 64 + lane;
        int row = ci >> 3, lc = (ci & 7) ^ (row & 7);
        stage16(&Kb[qkbase + (size_t)(j * 128 + row) * 1024 + lc * 8],
                &Ks[(wave * 4 + i) * 512], lane);
      }
      __syncthreads();   // b1: K drained; guards Vs(prev PV reads) vs V writes

      // ---- stage V; its drain at b2 hides under QK+softmax ----
#pragma unroll
      for (int i = 0; i < 4; ++i) {
        int ci = (wave * 4 + i) * 64 + lane;
        int d = ci >> 4, lc = (ci & 15) ^ (d & 15);
        stage16(&Vt[vbase + ((size_t)d << 11) + j * 128 + lc * 8],
                &Vs[(wave * 4 + i) * 512], lane);
      }

      const bool diag = (j == jmax);
      const int nlim = (diag && !(qt & 1)) ? 4 : 8;

      f32x4 s[8];
#pragma unroll
      for (int nt = 0; nt < 8; ++nt)
        if (nt < nlim) {
          f32x4 a = {0.f, 0.f, 0.f, 0.f};
#pragma unroll
          for (int kb = 0; kb < 2; ++kb) {
            int pc = (kb * 4 + quad) ^ (lr & 7);
            bf16x8 kf = *(const bf16x8*)&Ks[(nt * 16 + lr) * 64 + pc * 8];
            a = __builtin_amdgcn_mfma_f32_16x16x32_bf16(kf, qf[kb], a, 0, 0, 0);
          }
          s[nt] = a;
        }

      if (diag) {
#pragma unroll
        for (int nt = 0; nt < 8; ++nt)
          if (nt < nlim)
#pragma unroll
            for (int r = 0; r < 4; ++r) {
              int kpos = j * 128 + nt * 16 + quad * 4 + r;
              if (kpos > qrow) s[nt][r] = -1e30f;
            }
      }

      float mloc = -1e30f;
#pragma unroll
      for (int nt = 0; nt < 8; ++nt)
        if (nt < nlim)
#pragma unroll
          for (int r = 0; r < 4; ++r) mloc = fmaxf(mloc, s[nt][r]);
      mloc = fmaxf(mloc, __shfl_xor(mloc, 16, 64));
      mloc = fmaxf(mloc, __shfl_xor(mloc, 32, 64));
      float mnew = fmaxf(m_i, mloc);
      float alpha = exp2f(m_i - mnew);
      m_i = mnew;

      bf16x4 pk[8];
#pragma unroll
      for (int nt = 0; nt < 8; ++nt)
        if (nt < nlim) {
          float p0 = exp2f(s[nt][0] - mnew), p1 = exp2f(s[nt][1] - mnew);
          float p2 = exp2f(s[nt][2] - mnew), p3 = exp2f(s[nt][3] - mnew);
          u32x2 u = {pack_bf2(p0, p1), pack_bf2(p2, p3)};
          pk[nt] = __builtin_bit_cast(bf16x4, u);
        }

      float am[4];
#pragma unroll
      for (int r = 0; r < 4; ++r) am[r] = __shfl(alpha, quad * 4 + r, 16);
#pragma unroll
      for (int dt = 0; dt < 4; ++dt)
#pragma unroll
        for (int r = 0; r < 4; ++r) od[dt][r] *= am[r];
#pragma unroll
      for (int r = 0; r < 4; ++r) ol[r] *= am[r];

      __syncthreads();   // b2: V drained; Ks reads done -> next-iter K writes safe

      // ---- PV after b2 ----
#pragma unroll
      for (int nt = 0; nt < 8; ++nt)
        if (nt < nlim) {
#pragma unroll
          for (int dt = 0; dt < 4; ++dt) {
            int pc = (nt * 2 + (quad >> 1)) ^ lr;
            bf16x4 vf = *(const bf16x4*)&Vs[(dt * 16 + lr) * 128 + pc * 8 + (quad & 1) * 4];
            od[dt] = MFMA_K16(pk[nt], vf, od[dt]);
          }
          ol = MFMA_K16(pk[nt], ones, ol);
        }
    }

#pragma unroll
    for (int dt = 0; dt < 4; ++dt) {
      int col = h * 64 + dt * 16 + lr;
#pragma unroll
      for (int r = 0; r < 4; ++r) {
        int row = qrow0 + quad * 4 + r;
        ctx[((size_t)b * TT + row) * 1024 + col] = f2bf(od[dt][r] / ol[r]);
      }
    }
  }
}

// ---------------------------------------------------------------------------
// Output projection: 128x64 tiles -> 512 blocks (2/CU, cross-block overlap
// at K-loop barriers; was 1/CU). XCD-affine: xcd owns 4 bm-tiles x 16 bn.
// ---------------------------------------------------------------------------
__global__ __launch_bounds__(256) void gemm_out(
    const unsigned short* __restrict__ A,
    const unsigned short* __restrict__ Bw,
    const float* __restrict__ bias,
    float* __restrict__ out)
{
  __shared__ unsigned short pool[6144];      // As 4096 + Bs 2048
  unsigned short* As = pool;
  unsigned short* Bs = pool + 4096;

  const int tid = threadIdx.x, wave = tid >> 6, lane = tid & 63;
  const int lr = lane & 15, quad = lane >> 4;
  const int cblk = blockIdx.x;               // 0..511
  const int xcd = cblk & 7, kk = cblk >> 3;  // kk 0..63
  const int bm = (xcd + (kk >> 4) * 8) * 128;
  const int bn = (kk & 15) * 64;
  const int wm = (wave >> 1) * 64, wn = (wave & 1) * 32;

  f32x4 acc[4][2] = {};

  for (int k0 = 0; k0 < 1024; k0 += 32) {
    // B: 64 rows x 32 k = 256 chunks; each wave stages 64
    {
      int c = wave * 64 + lane;
      int row = c >> 2, l8 = (c & 3) ^ ((row >> 1) & 3);
      stage16(&Bw[(size_t)(bn + row) * 1024 + k0 + l8 * 8],
              &Bs[wave * 512], lane);
    }
    // A: 128 rows x 32 k = 512 chunks; each wave stages 128
#pragma unroll
    for (int i = 0; i < 2; ++i) {
      int c = wave * 128 + i * 64 + lane;
      int row = c >> 2, l8 = (c & 3) ^ ((row >> 1) & 3);
      stage16(&A[(size_t)(bm + row) * 1024 + k0 + l8 * 8],
              &As[(wave * 2 + i) * 512], lane);
    }
    __syncthreads();

    bf16x8 af[4], bf[2];
#pragma unroll
    for (int mt = 0; mt < 4; ++mt) {
      int row = wm + mt * 16 + lr;
      af[mt] = *(const bf16x8*)&As[row * 32 + (quad ^ ((row >> 1) & 3)) * 8];
    }
#pragma unroll
    for (int nt = 0; nt < 2; ++nt) {
      int row = wn + nt * 16 + lr;
      bf[nt] = *(const bf16x8*)&Bs[row * 32 + (quad ^ ((row >> 1) & 3)) * 8];
    }
#pragma unroll
    for (int mt = 0; mt < 4; ++mt)
#pragma unroll
      for (int nt = 0; nt < 2; ++nt)
        acc[mt][nt] = __builtin_amdgcn_mfma_f32_16x16x32_bf16(
            af[mt], bf[nt], acc[mt][nt], 0, 0, 0);
    __syncthreads();
  }

#pragma unroll
  for (int nt = 0; nt < 2; ++nt) {
    int col = bn + wn + nt * 16 + lr;
    float bv = bias[col];
#pragma unroll
    for (int mt = 0; mt < 4; ++mt) {
      int row = bm + wm + mt * 16 + quad * 4;
#pragma unroll
      for (int r = 0; r < 4; ++r)
        out[(size_t)(row + r) * 1024 + col] = acc[mt][nt][r] + bv;
    }
  }
}

// ---------------------------------------------------------------------------
extern "C" void kernel_launch(void* const* d_in, const int* in_sizes, int n_in,
                              void* d_out, int out_size, void* d_ws, size_t ws_size,
                              hipStream_t stream) {
  const float* x  = (const float*)d_in[0];
  const float* Wq = (const float*)d_in[1];
  const float* Wk = (const float*)d_in[2];
  const float* Wv = (const float*)d_in[3];
  const float* Wo = (const float*)d_in[4];
  const float* bo = (const float*)d_in[5];
  float* out = (float*)d_out;
  unsigned short* ws = (unsigned short*)d_ws;

  const size_t SZ = (size_t)MR * DD;         // 4096*1024

  // ws: [0] Q (ctx in-place)  [1] K  [2] Vt[b][h][d][t]  [3] Wb
  // xb (bf16 x, 8 MB) lives in d_out (16 MB fp32): dead until gemm_out's
  // final write, so the async-A staging path is ALWAYS available.
  unsigned short* Qb  = ws;
  unsigned short* Kbf = ws + SZ;
  unsigned short* Vt  = ws + 2 * SZ;
  unsigned short* Wb  = ws + 3 * SZ;
  unsigned short* xb  = (unsigned short*)d_out;

  cvt_all<<<dim3(4096), 256, 0, stream>>>(Wq, Wk, Wv, Wo, x, Wb, xb);
  gemm_qkv<<<dim3(768), 256, 0, stream>>>(xb, Wb, Qb, Kbf, Vt);
  attn<<<dim3(2 * NH * 16), 256, 0, stream>>>(Qb, Kbf, Vt, Qb);
  gemm_out<<<dim3(512), 256, 0, stream>>>(Qb, Wb + 3 * (size_t)DD * DD, bo, out);
}

// Round 17
// 184.772 us; speedup vs baseline: 1.0643x; 1.0461x over previous
//
#include <hip/hip_runtime.h>

// Problem constants
#define TT 2048
#define DD 1024
#define NH 16
#define DH 64
#define MR 4096            // B*T rows

typedef __attribute__((ext_vector_type(8))) short bf16x8;
typedef __attribute__((ext_vector_type(4))) short bf16x4;
typedef __attribute__((ext_vector_type(4))) float f32x4;
typedef __attribute__((ext_vector_type(2))) unsigned int u32x2;

__device__ __forceinline__ float bf2f(unsigned short u) {
  unsigned int x = ((unsigned int)u) << 16;
  return __builtin_bit_cast(float, x);
}
__device__ __forceinline__ unsigned short f2bf(float f) {
  unsigned int x = __builtin_bit_cast(unsigned int, f);
  x = (x + 0x7fffu + ((x >> 16) & 1u)) >> 16;
  return (unsigned short)x;
}
__device__ __forceinline__ unsigned int pack_bf2(float a, float b) {
#if __has_builtin(__builtin_amdgcn_cvt_pk_bf16_f32)
  typedef __attribute__((ext_vector_type(2))) __bf16 bf2_t;
  bf2_t v = __builtin_amdgcn_cvt_pk_bf16_f32(a, b);
  return __builtin_bit_cast(unsigned int, v);
#else
  return (unsigned int)f2bf(a) | ((unsigned int)f2bf(b) << 16);
#endif
}
__device__ __forceinline__ bf16x8 load8(const float* p) {
  bf16x8 r;
#pragma unroll
  for (int e = 0; e < 8; ++e) r[e] = (short)f2bf(p[e]);
  return r;
}

#if __has_builtin(__builtin_amdgcn_mfma_f32_16x16x16_bf16)
#define MFMA_K16(A, B, C) __builtin_amdgcn_mfma_f32_16x16x16_bf16(A, B, C, 0, 0, 0)
#else
#define MFMA_K16(A, B, C) __builtin_amdgcn_mfma_f32_16x16x16bf16_1k(A, B, C, 0, 0, 0)
#endif

// Async global->LDS 16B/lane; LDS base wave-uniform, HW adds lane*16.
__device__ __forceinline__ void stage16(const unsigned short* g,
                                        unsigned short* lbase, int lane) {
#if __has_builtin(__builtin_amdgcn_global_load_lds)
  __builtin_amdgcn_global_load_lds(
      (const __attribute__((address_space(1))) unsigned int*)g,
      (__attribute__((address_space(3))) unsigned int*)(lbase + lane * 8),
      16, 0, 0);
#else
  *(bf16x8*)(lbase + lane * 8) = *(const bf16x8*)g;
#endif
}

// ---------------------------------------------------------------------------
// Convert: Wb rows = [Wk; Wq; Wv; Wo] (reference Q/K swap!) + x -> xb.
// xb lives in d_out (dead until gemm_out) so the async-A path is guaranteed.
// ---------------------------------------------------------------------------
__global__ __launch_bounds__(256) void cvt_all(
    const float* __restrict__ Wq, const float* __restrict__ Wk,
    const float* __restrict__ Wv, const float* __restrict__ Wo,
    const float* __restrict__ x,
    unsigned short* __restrict__ Wb, unsigned short* __restrict__ xb)
{
  int c = blockIdx.x * 256 + threadIdx.x;     // chunk of 8 elems
  if (c < 524288) {
    int idx = c * 8, n = idx >> 10, col = idx & 1023;
    const float* src = (n < 1024) ? Wk + (size_t)n * 1024
                     : (n < 2048) ? Wq + (size_t)(n - 1024) * 1024
                     : (n < 3072) ? Wv + (size_t)(n - 2048) * 1024
                                  : Wo + (size_t)(n - 3072) * 1024;
    *(bf16x8*)&Wb[idx] = load8(src + col);
  } else {
    size_t idx = (size_t)(c - 524288) * 8;
    *(bf16x8*)&xb[idx] = load8(&x[idx]);
  }
}

// ---------------------------------------------------------------------------
// Fused QKV projection, BK=64 (half the barriers of R16's BK=32; 32 MFMA
// per stage), XCD-affine decode, both operands async-staged. LDS 32KB ->
// occupancy still VGPR-limited (~3 blocks/CU), no cliff. 8-chunk rows with
// lc = (c&7)^(row&7) swizzle: staging writes contiguous, fragment reads
// spread evenly over all 32 banks.
// ---------------------------------------------------------------------------
__global__ __launch_bounds__(256) void gemm_qkv(
    const unsigned short* __restrict__ xb,
    const unsigned short* __restrict__ Wb,
    unsigned short* __restrict__ Q, unsigned short* __restrict__ Kb,
    unsigned short* __restrict__ Vt)
{
  __shared__ unsigned short pool[16384];     // As(8192)+Bs(8192) | Tt(8704)
  unsigned short* As = pool;
  unsigned short* Bs = pool + 8192;

  const int tid = threadIdx.x, wave = tid >> 6, lane = tid & 63;
  const int lr = lane & 15, quad = lane >> 4;
  const int cblk = blockIdx.x;               // 0..767
  const int xcd = cblk & 7, kk = cblk >> 3;  // kk 0..95
  const int bm = (xcd + (kk / 24) * 8) * 128;
  const int bn = (kk % 24) * 128;
  const int wm = (wave >> 1) * 64, wn = (wave & 1) * 64;

  f32x4 acc[4][4] = {};

  for (int k0 = 0; k0 < 1024; k0 += 64) {
    // stage 128 rows x 64 k (8 chunks/row) per operand: 4 glds/thread each
#pragma unroll
    for (int i = 0; i < 4; ++i) {
      int ci = (wave * 4 + i) * 64 + lane;   // chunk 0..1023
      int row = ci >> 3, lc = (ci & 7) ^ (row & 7);
      stage16(&Wb[(size_t)(bn + row) * 1024 + k0 + lc * 8],
              &Bs[(wave * 4 + i) * 512], lane);
      stage16(&xb[(size_t)(bm + row) * 1024 + k0 + lc * 8],
              &As[(wave * 4 + i) * 512], lane);
    }
    __syncthreads();

#pragma unroll
    for (int ks = 0; ks < 2; ++ks) {         // two K=32 sub-steps
      bf16x8 af[4], bf[4];
#pragma unroll
      for (int mt = 0; mt < 4; ++mt) {
        int row = wm + mt * 16 + lr;
        int pc = (ks * 4 + quad) ^ (row & 7);
        af[mt] = *(const bf16x8*)&As[row * 64 + pc * 8];
      }
#pragma unroll
      for (int nt = 0; nt < 4; ++nt) {
        int row = wn + nt * 16 + lr;
        int pc = (ks * 4 + quad) ^ (row & 7);
        bf[nt] = *(const bf16x8*)&Bs[row * 64 + pc * 8];
      }
#pragma unroll
      for (int mt = 0; mt < 4; ++mt)
#pragma unroll
        for (int nt = 0; nt < 4; ++nt)
          acc[mt][nt] = __builtin_amdgcn_mfma_f32_16x16x32_bf16(
              af[mt], bf[nt], acc[mt][nt], 0, 0, 0);
    }
    __syncthreads();
  }

  if (bn < 2048) {
    unsigned short* Cp = (bn < 1024) ? Q : Kb;
    int coff = (bn < 1024) ? bn : bn - 1024;
#pragma unroll
    for (int nt = 0; nt < 4; ++nt) {
      int col = coff + wn + nt * 16 + lr;
#pragma unroll
      for (int mt = 0; mt < 4; ++mt) {
        int row = bm + wm + mt * 16 + quad * 4;
#pragma unroll
        for (int r = 0; r < 4; ++r)
          Cp[(size_t)(row + r) * 1024 + col] = f2bf(acc[mt][nt][r]);
      }
    }
  } else {
    const int b = bm >> 11, t0 = bm & 2047, d0 = bn - 2048;
    unsigned short* Tt = pool;               // [64][136]
#pragma unroll
    for (int hv = 0; hv < 2; ++hv) {
      __syncthreads();
      if ((wave & 1) == hv) {
#pragma unroll
        for (int nt = 0; nt < 4; ++nt)
#pragma unroll
          for (int mt = 0; mt < 4; ++mt) {
            // pack 4 rows (r contiguous) into one 8B write
            u32x2 u = {pack_bf2(acc[mt][nt][0], acc[mt][nt][1]),
                       pack_bf2(acc[mt][nt][2], acc[mt][nt][3])};
            *(u32x2*)&Tt[(nt * 16 + lr) * 136 + wm + mt * 16 + quad * 4] = u;
          }
      }
      __syncthreads();
#pragma unroll
      for (int ch = 0; ch < 4; ++ch) {
        int cc = tid + ch * 256;
        int d64 = cc >> 4, t8 = cc & 15;
        int dg = d0 + hv * 64 + d64;
        int h = dg >> 6, d = dg & 63;
        bf16x8 v = *(const bf16x8*)&Tt[d64 * 136 + t8 * 8];
        *(bf16x8*)&Vt[(((size_t)(b * NH + h) * 64 + d) << 11) + t0 + t8 * 8] = v;
      }
    }
  }
}

// ---------------------------------------------------------------------------
// Flash attention (R16 verbatim: split-barrier staging, XCD-affine bh
// decode, Sᵀ formulation, packed-bf16 P, MFMA-ones l, p<->31-p pairing).
// LDS-read-BW bound at ~2KB LDS-read per q-row — structural at 16 rows/wave.
// ---------------------------------------------------------------------------
__global__ __launch_bounds__(256) void attn(
    const unsigned short* __restrict__ Q,
    const unsigned short* __restrict__ Kb,
    const unsigned short* __restrict__ Vt,
    unsigned short* __restrict__ ctx)
{
  __shared__ unsigned short Ks[128 * 64];    // [kseq][d]   8 chunks/row
  __shared__ unsigned short Vs[64 * 128];    // [d][t]     16 chunks/row

  const int tid = threadIdx.x, wave = tid >> 6, lane = tid & 63;
  const int lr = lane & 15, quad = lane >> 4;
  const int p  = blockIdx.x >> 5;                               // 0..15
  const int bh = (blockIdx.x & 7) | (((blockIdx.x >> 3) & 3) << 3);
  const int h = bh & 15, b = bh >> 4;

  const size_t qkbase = ((size_t)b * TT) * 1024 + h * 64;
  const size_t vbase  = ((size_t)(b * NH + h) * 64) << 11;
  const float QS = 0.125f * 1.44269504f;     // scale * log2(e)

  bf16x4 ones;
#pragma unroll
  for (int e = 0; e < 4; ++e) ones[e] = (short)0x3F80;   // bf16 1.0

#pragma unroll
  for (int pass = 0; pass < 2; ++pass) {
    const int qt = pass ? p : (31 - p);
    const int qrow0 = qt * 64 + wave * 16;
    const int qrow  = qrow0 + lr;

    bf16x8 qf[2];
#pragma unroll
    for (int kb = 0; kb < 2; ++kb) {
      bf16x8 raw = *(const bf16x8*)&Q[qkbase + (size_t)(qrow0 + lr) * 1024 + kb * 32 + quad * 8];
#pragma unroll
      for (int e = 0; e < 8; ++e)
        qf[kb][e] = (short)f2bf(bf2f((unsigned short)raw[e]) * QS);
    }

    float m_i = -1e30f;
    f32x4 od[4] = {};
    f32x4 ol = {};
    const int jmax = qt >> 1;

    for (int j = 0; j <= jmax; ++j) {
      // ---- stage K, drain at barrier1 ----
#pragma unroll
      for (int i = 0; i < 4; ++i) {
        int ci = (wave * 4 + i) * 64 + lane;
        int row = ci >> 3, lc = (ci & 7) ^ (row & 7);
        stage16(&Kb[qkbase + (size_t)(j * 128 + row) * 1024 + lc * 8],
                &Ks[(wave * 4 + i) * 512], lane);
      }
      __syncthreads();   // b1: K drained; guards Vs(prev PV reads) vs V writes

      // ---- stage V; its drain at b2 hides under QK+softmax ----
#pragma unroll
      for (int i = 0; i < 4; ++i) {
        int ci = (wave * 4 + i) * 64 + lane;
        int d = ci >> 4, lc = (ci & 15) ^ (d & 15);
        stage16(&Vt[vbase + ((size_t)d << 11) + j * 128 + lc * 8],
                &Vs[(wave * 4 + i) * 512], lane);
      }

      const bool diag = (j == jmax);
      const int nlim = (diag && !(qt & 1)) ? 4 : 8;

      f32x4 s[8];
#pragma unroll
      for (int nt = 0; nt < 8; ++nt)
        if (nt < nlim) {
          f32x4 a = {0.f, 0.f, 0.f, 0.f};
#pragma unroll
          for (int kb = 0; kb < 2; ++kb) {
            int pc = (kb * 4 + quad) ^ (lr & 7);
            bf16x8 kf = *(const bf16x8*)&Ks[(nt * 16 + lr) * 64 + pc * 8];
            a = __builtin_amdgcn_mfma_f32_16x16x32_bf16(kf, qf[kb], a, 0, 0, 0);
          }
          s[nt] = a;
        }

      if (diag) {
#pragma unroll
        for (int nt = 0; nt < 8; ++nt)
          if (nt < nlim)
#pragma unroll
            for (int r = 0; r < 4; ++r) {
              int kpos = j * 128 + nt * 16 + quad * 4 + r;
              if (kpos > qrow) s[nt][r] = -1e30f;
            }
      }

      float mloc = -1e30f;
#pragma unroll
      for (int nt = 0; nt < 8; ++nt)
        if (nt < nlim)
#pragma unroll
          for (int r = 0; r < 4; ++r) mloc = fmaxf(mloc, s[nt][r]);
      mloc = fmaxf(mloc, __shfl_xor(mloc, 16, 64));
      mloc = fmaxf(mloc, __shfl_xor(mloc, 32, 64));
      float mnew = fmaxf(m_i, mloc);
      float alpha = exp2f(m_i - mnew);
      m_i = mnew;

      bf16x4 pk[8];
#pragma unroll
      for (int nt = 0; nt < 8; ++nt)
        if (nt < nlim) {
          float p0 = exp2f(s[nt][0] - mnew), p1 = exp2f(s[nt][1] - mnew);
          float p2 = exp2f(s[nt][2] - mnew), p3 = exp2f(s[nt][3] - mnew);
          u32x2 u = {pack_bf2(p0, p1), pack_bf2(p2, p3)};
          pk[nt] = __builtin_bit_cast(bf16x4, u);
        }

      float am[4];
#pragma unroll
      for (int r = 0; r < 4; ++r) am[r] = __shfl(alpha, quad * 4 + r, 16);
#pragma unroll
      for (int dt = 0; dt < 4; ++dt)
#pragma unroll
        for (int r = 0; r < 4; ++r) od[dt][r] *= am[r];
#pragma unroll
      for (int r = 0; r < 4; ++r) ol[r] *= am[r];

      __syncthreads();   // b2: V drained; Ks reads done -> next-iter K writes safe

      // ---- PV after b2 ----
#pragma unroll
      for (int nt = 0; nt < 8; ++nt)
        if (nt < nlim) {
#pragma unroll
          for (int dt = 0; dt < 4; ++dt) {
            int pc = (nt * 2 + (quad >> 1)) ^ lr;
            bf16x4 vf = *(const bf16x4*)&Vs[(dt * 16 + lr) * 128 + pc * 8 + (quad & 1) * 4];
            od[dt] = MFMA_K16(pk[nt], vf, od[dt]);
          }
          ol = MFMA_K16(pk[nt], ones, ol);
        }
    }

#pragma unroll
    for (int dt = 0; dt < 4; ++dt) {
      int col = h * 64 + dt * 16 + lr;
#pragma unroll
      for (int r = 0; r < 4; ++r) {
        int row = qrow0 + quad * 4 + r;
        ctx[((size_t)b * TT + row) * 1024 + col] = f2bf(od[dt][r] / ol[r]);
      }
    }
  }
}

// ---------------------------------------------------------------------------
// Output projection: BK=64 (16 iters, 16 MFMA/iter), 128x64 tiles, 512
// blocks (2/CU), XCD-affine decode. LDS 24KB.
// ---------------------------------------------------------------------------
__global__ __launch_bounds__(256) void gemm_out(
    const unsigned short* __restrict__ A,
    const unsigned short* __restrict__ Bw,
    const float* __restrict__ bias,
    float* __restrict__ out)
{
  __shared__ unsigned short pool[12288];     // As 8192 + Bs 4096
  unsigned short* As = pool;
  unsigned short* Bs = pool + 8192;

  const int tid = threadIdx.x, wave = tid >> 6, lane = tid & 63;
  const int lr = lane & 15, quad = lane >> 4;
  const int cblk = blockIdx.x;               // 0..511
  const int xcd = cblk & 7, kk = cblk >> 3;  // kk 0..63
  const int bm = (xcd + (kk >> 4) * 8) * 128;
  const int bn = (kk & 15) * 64;
  const int wm = (wave >> 1) * 64, wn = (wave & 1) * 32;

  f32x4 acc[4][2] = {};

  for (int k0 = 0; k0 < 1024; k0 += 64) {
    // B: 64 rows x 8 chunks = 512 chunks -> 2/thread
#pragma unroll
    for (int i = 0; i < 2; ++i) {
      int ci = (wave * 2 + i) * 64 + lane;
      int row = ci >> 3, lc = (ci & 7) ^ (row & 7);
      stage16(&Bw[(size_t)(bn + row) * 1024 + k0 + lc * 8],
              &Bs[(wave * 2 + i) * 512], lane);
    }
    // A: 128 rows x 8 chunks = 1024 chunks -> 4/thread
#pragma unroll
    for (int i = 0; i < 4; ++i) {
      int ci = (wave * 4 + i) * 64 + lane;
      int row = ci >> 3, lc = (ci & 7) ^ (row & 7);
      stage16(&A[(size_t)(bm + row) * 1024 + k0 + lc * 8],
              &As[(wave * 4 + i) * 512], lane);
    }
    __syncthreads();

#pragma unroll
    for (int ks = 0; ks < 2; ++ks) {
      bf16x8 af[4], bf[2];
#pragma unroll
      for (int mt = 0; mt < 4; ++mt) {
        int row = wm + mt * 16 + lr;
        int pc = (ks * 4 + quad) ^ (row & 7);
        af[mt] = *(const bf16x8*)&As[row * 64 + pc * 8];
      }
#pragma unroll
      for (int nt = 0; nt < 2; ++nt) {
        int row = wn + nt * 16 + lr;
        int pc = (ks * 4 + quad) ^ (row & 7);
        bf[nt] = *(const bf16x8*)&Bs[row * 64 + pc * 8];
      }
#pragma unroll
      for (int mt = 0; mt < 4; ++mt)
#pragma unroll
        for (int nt = 0; nt < 2; ++nt)
          acc[mt][nt] = __builtin_amdgcn_mfma_f32_16x16x32_bf16(
              af[mt], bf[nt], acc[mt][nt], 0, 0, 0);
    }
    __syncthreads();
  }

#pragma unroll
  for (int nt = 0; nt < 2; ++nt) {
    int col = bn + wn + nt * 16 + lr;
    float bv = bias[col];
#pragma unroll
    for (int mt = 0; mt < 4; ++mt) {
      int row = bm + wm + mt * 16 + quad * 4;
#pragma unroll
      for (int r = 0; r < 4; ++r)
        out[(size_t)(row + r) * 1024 + col] = acc[mt][nt][r] + bv;
    }
  }
}

// ---------------------------------------------------------------------------
extern "C" void kernel_launch(void* const* d_in, const int* in_sizes, int n_in,
                              void* d_out, int out_size, void* d_ws, size_t ws_size,
                              hipStream_t stream) {
  const float* x  = (const float*)d_in[0];
  const float* Wq = (const float*)d_in[1];
  const float* Wk = (const float*)d_in[2];
  const float* Wv = (const float*)d_in[3];
  const float* Wo = (const float*)d_in[4];
  const float* bo = (const float*)d_in[5];
  float* out = (float*)d_out;
  unsigned short* ws = (unsigned short*)d_ws;

  const size_t SZ = (size_t)MR * DD;         // 4096*1024

  // ws: [0] Q (ctx in-place)  [1] K  [2] Vt[b][h][d][t]  [3] Wb
  // xb (bf16 x, 8 MB) lives in d_out (16 MB fp32): dead until gemm_out's
  // final write, so the async-A staging path is ALWAYS available.
  unsigned short* Qb  = ws;
  unsigned short* Kbf = ws + SZ;
  unsigned short* Vt  = ws + 2 * SZ;
  unsigned short* Wb  = ws + 3 * SZ;
  unsigned short* xb  = (unsigned short*)d_out;

  cvt_all<<<dim3(4096), 256, 0, stream>>>(Wq, Wk, Wv, Wo, x, Wb, xb);
  gemm_qkv<<<dim3(768), 256, 0, stream>>>(xb, Wb, Qb, Kbf, Vt);
  attn<<<dim3(2 * NH * 16), 256, 0, stream>>>(Qb, Kbf, Vt, Qb);
  gemm_out<<<dim3(512), 256, 0, stream>>>(Qb, Wb + 3 * (size_t)DD * DD, bo, out);
}